// Round 4
// baseline (61.041 us; speedup 1.0000x reference)
//
#include <hip/hip_runtime.h>

#define N_ROWS 131072
#define D_COLS 256
#define B_SEG  16
#define ROWS_PER_WAVE 16
#define BLK_THREADS 512                      // 8 waves/block
#define ROWS_PER_BLOCK (ROWS_PER_WAVE * BLK_THREADS / 64)   // 128
#define NBLK (N_ROWS / ROWS_PER_BLOCK)       // 1024

// One wave (64 lanes) handles ROWS_PER_WAVE contiguous rows.
// Lane l loads float4 at column 4*l: 64 lanes * 16B = 256 floats = one row.
// Block combines its 8 waves in LDS, then writes a private 32-float partial
// line acc[blockIdx][32] unconditionally (no global atomics, no memset).
__global__ __launch_bounds__(BLK_THREADS) void umse_main(
    const float* __restrict__ input,
    const float* __restrict__ target,
    const int*   __restrict__ batch,
    float*       __restrict__ acc /* [NBLK][B_SEG*2] */) {

    __shared__ float lacc[B_SEG * 2];
    const int tid  = threadIdx.x;
    const int lane = tid & 63;
    if (tid < B_SEG * 2) lacc[tid] = 0.f;
    __syncthreads();

    const int wave = (blockIdx.x * BLK_THREADS + tid) >> 6;
    const long row0 = (long)wave * ROWS_PER_WAVE;

    const float4* __restrict__ in4 = (const float4*)input;
    const float4* __restrict__ tg4 = (const float4*)target;

    const int b0 = batch[row0];
    const int b1 = batch[row0 + ROWS_PER_WAVE - 1];

    if (b0 == b1) {
        // ---- fast path: whole chunk in one segment (8177+ of 8192 waves) ----
        float rp0 = 0.f, rn0 = 0.f, rp1 = 0.f, rn1 = 0.f;
        float rp2 = 0.f, rn2 = 0.f, rp3 = 0.f, rn3 = 0.f;
        #pragma unroll
        for (int i = 0; i < ROWS_PER_WAVE; i += 4) {
            const long base = (row0 + i) * (D_COLS / 4) + lane;
            const float4 x0 = in4[base];
            const float4 t0 = tg4[base];
            const float4 x1 = in4[base + 1 * (D_COLS / 4)];
            const float4 t1 = tg4[base + 1 * (D_COLS / 4)];
            const float4 x2 = in4[base + 2 * (D_COLS / 4)];
            const float4 t2 = tg4[base + 2 * (D_COLS / 4)];
            const float4 x3 = in4[base + 3 * (D_COLS / 4)];
            const float4 t3 = tg4[base + 3 * (D_COLS / 4)];

            float d;
            d = x0.x - t0.x; rp0 += d * d;  d = x0.x + t0.x; rn0 += d * d;
            d = x0.y - t0.y; rp0 += d * d;  d = x0.y + t0.y; rn0 += d * d;
            d = x0.z - t0.z; rp0 += d * d;  d = x0.z + t0.z; rn0 += d * d;
            d = x0.w - t0.w; rp0 += d * d;  d = x0.w + t0.w; rn0 += d * d;

            d = x1.x - t1.x; rp1 += d * d;  d = x1.x + t1.x; rn1 += d * d;
            d = x1.y - t1.y; rp1 += d * d;  d = x1.y + t1.y; rn1 += d * d;
            d = x1.z - t1.z; rp1 += d * d;  d = x1.z + t1.z; rn1 += d * d;
            d = x1.w - t1.w; rp1 += d * d;  d = x1.w + t1.w; rn1 += d * d;

            d = x2.x - t2.x; rp2 += d * d;  d = x2.x + t2.x; rn2 += d * d;
            d = x2.y - t2.y; rp2 += d * d;  d = x2.y + t2.y; rn2 += d * d;
            d = x2.z - t2.z; rp2 += d * d;  d = x2.z + t2.z; rn2 += d * d;
            d = x2.w - t2.w; rp2 += d * d;  d = x2.w + t2.w; rn2 += d * d;

            d = x3.x - t3.x; rp3 += d * d;  d = x3.x + t3.x; rn3 += d * d;
            d = x3.y - t3.y; rp3 += d * d;  d = x3.y + t3.y; rn3 += d * d;
            d = x3.z - t3.z; rp3 += d * d;  d = x3.z + t3.z; rn3 += d * d;
            d = x3.w - t3.w; rp3 += d * d;  d = x3.w + t3.w; rn3 += d * d;
        }
        float rp = (rp0 + rp1) + (rp2 + rp3);
        float rn = (rn0 + rn1) + (rn2 + rn3);
        #pragma unroll
        for (int off = 32; off; off >>= 1) {
            rp += __shfl_down(rp, off);
            rn += __shfl_down(rn, off);
        }
        if (lane == 0) {
            atomicAdd(&lacc[b0 * 2 + 0], rp);   // LDS atomic
            atomicAdd(&lacc[b0 * 2 + 1], rn);
        }
    } else {
        // ---- slow path: chunk straddles a segment boundary (<=15 waves) ----
        for (int i = 0; i < ROWS_PER_WAVE; ++i) {
            const long r = row0 + i;
            const int b = batch[r];
            const float4 x = in4[r * (D_COLS / 4) + lane];
            const float4 t = tg4[r * (D_COLS / 4) + lane];
            float d;
            float p = 0.f, n = 0.f;
            d = x.x - t.x; p += d * d;  d = x.x + t.x; n += d * d;
            d = x.y - t.y; p += d * d;  d = x.y + t.y; n += d * d;
            d = x.z - t.z; p += d * d;  d = x.z + t.z; n += d * d;
            d = x.w - t.w; p += d * d;  d = x.w + t.w; n += d * d;
            #pragma unroll
            for (int off = 32; off; off >>= 1) {
                p += __shfl_down(p, off);
                n += __shfl_down(n, off);
            }
            if (lane == 0) {
                atomicAdd(&lacc[b * 2 + 0], p);
                atomicAdd(&lacc[b * 2 + 1], n);
            }
        }
    }

    __syncthreads();
    if (tid < B_SEG * 2) {
        acc[(long)blockIdx.x * (B_SEG * 2) + tid] = lacc[tid];  // 128 B coalesced store
    }
}

// Reduce acc[NBLK][32] -> out = sum_b min(lp[b], ln[b]).  One 1024-thread block.
__global__ __launch_bounds__(1024) void umse_final(
    const float* __restrict__ acc, float* __restrict__ out) {
    __shared__ float sums[32][B_SEG * 2];
    const int tid = threadIdx.x;          // 0..1023
    const int val = tid & 31;
    const int grp = tid >> 5;             // 0..31
    float s = 0.f;
    for (int bl = grp; bl < NBLK; bl += 32)
        s += acc[bl * (B_SEG * 2) + val];  // coalesced: 256 B per wave per iter
    sums[grp][val] = s;
    __syncthreads();
    if (tid < 64) {
        float total = 0.f;
        if (tid < B_SEG * 2) {
            #pragma unroll
            for (int g = 0; g < 32; ++g)
                total += sums[g][tid];
        }
        const float partner = __shfl_xor(total, 1);
        const float m = fminf(total, partner);
        float contrib = ((tid < B_SEG * 2) && ((tid & 1) == 0)) ? m : 0.f;
        #pragma unroll
        for (int off = 32; off; off >>= 1)
            contrib += __shfl_down(contrib, off);
        if (tid == 0) out[0] = contrib;
    }
}

extern "C" void kernel_launch(void* const* d_in, const int* in_sizes, int n_in,
                              void* d_out, int out_size, void* d_ws, size_t ws_size,
                              hipStream_t stream) {
    const float* input  = (const float*)d_in[0];
    const float* target = (const float*)d_in[1];
    const int*   batch  = (const int*)d_in[2];
    float* acc = (float*)d_ws;   // NBLK*32*4 = 128 KB of scratch, written unconditionally

    umse_main<<<NBLK, BLK_THREADS, 0, stream>>>(input, target, batch, acc);
    umse_final<<<1, 1024, 0, stream>>>(acc, (float*)d_out);
}